// Round 21
// baseline (181.724 us; speedup 1.0000x reference)
//
#include <hip/hip_runtime.h>
#include <hip/hip_bf16.h>
#include <math.h>

#define T_SEQ 4096
#define C_EMB 768
#define NHEAD 12
#define HDIM  64
#define NZ    2   // key-split (R19-proven)

typedef __bf16 bf16;
typedef __bf16 bf16x8 __attribute__((ext_vector_type(8)));
typedef __bf16 bf16x4 __attribute__((ext_vector_type(4)));
typedef float  f32x4  __attribute__((ext_vector_type(4)));
typedef float  f32x16 __attribute__((ext_vector_type(16)));

#if __has_builtin(__builtin_amdgcn_exp2f)
#define EXP2 __builtin_amdgcn_exp2f
#else
#define EXP2 exp2f
#endif

// ---------------------------------------------------------------- utilities

__device__ __forceinline__ void stage16(const void* g, void* ldsbase) {
  // global -> LDS direct, 16B per lane; LDS dest = wave-uniform base + lane*16
  __builtin_amdgcn_global_load_lds(
      (__attribute__((address_space(1))) const unsigned int*)g,
      (__attribute__((address_space(3))) unsigned int*)ldsbase, 16, 0, 0);
}

__device__ __forceinline__ f32x16 zero16() {
  f32x16 z;
#pragma unroll
  for (int i = 0; i < 16; i++) z[i] = 0.f;
  return z;
}

// ------------------------------------------------------------- prep kernel
// Fuses the 4 weight transposes (f32 [K][N] -> bf16 [N][K]) and the first
// layernorm into ONE launch (they are mutually independent).
__device__ __forceinline__ void do_transpose(const float* __restrict__ W,
                                             bf16* __restrict__ Wt, int K, int N,
                                             int bx, int by, int tid,
                                             float (*tile)[33]) {
  const int n0 = bx * 32, k0 = by * 32;
  const int tx = tid & 31, ty = tid >> 5;  // 256 thr: ty 0..7
#pragma unroll
  for (int i = 0; i < 32; i += 8)
    tile[ty + i][tx] = W[(size_t)(k0 + ty + i) * N + n0 + tx];
  __syncthreads();
#pragma unroll
  for (int i = 0; i < 32; i += 8)
    Wt[(size_t)(n0 + ty + i) * K + k0 + tx] = (bf16)tile[tx][ty + i];
}

__device__ __forceinline__ void do_ln(const float* __restrict__ x,
                                      bf16* __restrict__ y, int row, int t,
                                      float* red) {
  const float* xr = x + (size_t)row * C_EMB;
  float v0 = xr[t], v1 = xr[t + 256], v2 = xr[t + 512];
  float s  = v0 + v1 + v2;
  float ss = v0 * v0 + v1 * v1 + v2 * v2;
#pragma unroll
  for (int m = 1; m < 64; m <<= 1) {
    s += __shfl_xor(s, m);
    ss += __shfl_xor(ss, m);
  }
  const int w = t >> 6;
  if ((t & 63) == 0) { red[w] = s; red[4 + w] = ss; }
  __syncthreads();
  s  = red[0] + red[1] + red[2] + red[3];
  ss = red[4] + red[5] + red[6] + red[7];
  const float mu  = s * (1.0f / C_EMB);
  const float var = ss * (1.0f / C_EMB) - mu * mu;
  const float rs  = rsqrtf(var + 1e-5f);
  bf16* yr = y + (size_t)row * C_EMB;
  yr[t]       = (bf16)((v0 - mu) * rs);
  yr[t + 256] = (bf16)((v1 - mu) * rs);
  yr[t + 512] = (bf16)((v2 - mu) * rs);
}

__global__ void prep(const float* __restrict__ x, bf16* __restrict__ ln_out,
                     const float* __restrict__ W_kqv, bf16* __restrict__ Wkqv_t,
                     const float* __restrict__ W_proj, bf16* __restrict__ Wproj_t,
                     const float* __restrict__ W_fc, bf16* __restrict__ Wfc_t,
                     const float* __restrict__ W_cproj, bf16* __restrict__ Wcp_t) {
  __shared__ float tile[32][33];
  const int b = blockIdx.x, t = threadIdx.x;
  if (b < 1728) {
    do_transpose(W_kqv, Wkqv_t, 768, 2304, b % 72, b / 72, t, tile);
  } else if (b < 2304) {
    const int bb = b - 1728;
    do_transpose(W_proj, Wproj_t, 768, 768, bb % 24, bb / 24, t, tile);
  } else if (b < 3456) {
    const int bb = b - 2304;
    do_transpose(W_fc, Wfc_t, 768, 1536, bb % 48, bb / 48, t, tile);
  } else if (b < 4608) {
    const int bb = b - 3456;
    do_transpose(W_cproj, Wcp_t, 1536, 768, bb % 24, bb / 24, t, tile);
  } else {
    do_ln(x, ln_out, b - 4608, t, &tile[0][0]);
  }
}

// ------------------------------------------------------------------ layernorm2
// x1 [4096][768] bf16 -> y bf16. Wave-per-row (no LDS, no syncthreads):
// lane owns 12 elems (bf16x8 @ l*8 + bf16x4 @ 512+l*4), shfl_xor reduce.
// 4 rows per 256-thread block.
__global__ void ln_rows(const bf16* __restrict__ x, bf16* __restrict__ y) {
  const int w = threadIdx.x >> 6, l = threadIdx.x & 63;
  const int row = blockIdx.x * 4 + w;
  const bf16* xr = x + (size_t)row * C_EMB;
  const bf16x8 v8 = *reinterpret_cast<const bf16x8*>(xr + l * 8);
  const bf16x4 v4 = *reinterpret_cast<const bf16x4*>(xr + 512 + l * 4);
  float f[12];
#pragma unroll
  for (int j = 0; j < 8; j++) f[j] = (float)v8[j];
#pragma unroll
  for (int j = 0; j < 4; j++) f[8 + j] = (float)v4[j];
  float s = 0.f, ss = 0.f;
#pragma unroll
  for (int j = 0; j < 12; j++) { s += f[j]; ss += f[j] * f[j]; }
#pragma unroll
  for (int m = 1; m < 64; m <<= 1) {
    s += __shfl_xor(s, m);
    ss += __shfl_xor(ss, m);
  }
  const float mu  = s * (1.0f / C_EMB);
  const float var = ss * (1.0f / C_EMB) - mu * mu;
  const float rs  = rsqrtf(var + 1e-5f);
  bf16x8 o8;
  bf16x4 o4;
#pragma unroll
  for (int j = 0; j < 8; j++) o8[j] = (bf16)((f[j] - mu) * rs);
#pragma unroll
  for (int j = 0; j < 4; j++) o4[j] = (bf16)((f[8 + j] - mu) * rs);
  bf16* yr = y + (size_t)row * C_EMB;
  *reinterpret_cast<bf16x8*>(yr + l * 8) = o8;
  *reinterpret_cast<bf16x4*>(yr + 512 + l * 4) = o4;
}

// ------------------------------------------------------------------ GEMM
// C[M][N] = A[M][K](bf16 rowmajor) x BT[N][K](bf16)   (i.e. A @ B)
// Single-buffer m97 pattern, BK=64, BN=64. Template BM in {64,128}:
// BM=64 doubles block count (latency-bound shapes want blocks: R11 BN win,
// R20 BM win for proj/fc/cproj, now applied to kqv too -> 9 blocks/CU).
// Wave = (BM/2)x32, acc (BM/32)x2. XCD-aware 1D grid (bijective, nrow%8==0).
// EPI 0: store bf16                  EPI 1: bf16 = res_f32 + acc  (x1 resid)
// EPI 2: bf16 = gelu(acc + bias[c])  EPI 3: f32 = res_bf16 + acc  (output)
// EPI 4: bf16 store, cols [768,1536) scaled by 0.125*log2e (kqv Q pre-scale)
template <int EPI, int BM>
__global__ void gemm_bt(const bf16* __restrict__ A, const bf16* __restrict__ BT,
                        void* __restrict__ Cout, const void* __restrict__ res,
                        const float* __restrict__ bias, int M, int N, int K) {
  __shared__ __align__(16) bf16 As[BM * 64];
  __shared__ __align__(16) bf16 Bs[64 * 64];
  constexpr int MR = BM / 32;           // A fragments (rows of 16) per wave
  // ---- XCD-aware decode: xcd = bid&7 owns nrow/8 row-panels x all cols
  const int nrow = M / BM;
  const int ncol = N >> 6;
  const int rpx = nrow >> 3;
  const int bid = blockIdx.x;
  const int xcd = bid & 7, idx = bid >> 3;
  const int rowb = xcd * rpx + idx / ncol;
  const int colb = idx % ncol;
  const int row0 = rowb * BM, col0 = colb * 64;

  const int tid = threadIdx.x;
  const int w = tid >> 6, lane = tid & 63;
  const int wr = w >> 1, wc = w & 1;
  const int l15 = lane & 15, l4 = lane >> 4;

  f32x4 acc[MR][2];
#pragma unroll
  for (int m = 0; m < MR; m++)
#pragma unroll
    for (int n = 0; n < 2; n++) acc[m][n] = (f32x4){0.f, 0.f, 0.f, 0.f};

  const int rr = lane >> 3;        // 8 rows per 1KB wave-instr (128B rows)
  const int c8 = (lane & 7) * 8;   // 8 chunks of 8 bf16 per 128B row

  for (int k0 = 0; k0 < K; k0 += 64) {
    const bf16* gA = A + (size_t)(row0 + w * (BM / 4) + rr) * K + k0 + c8;
    const bf16* gB = BT + (size_t)(col0 + w * 16 + rr) * K + k0 + c8;
#pragma unroll
    for (int i = 0; i < BM / 32; i++)
      stage16(gA + (size_t)(8 * i) * K, As + (w * (BM / 4) + 8 * i) * 64);
#pragma unroll
    for (int i = 0; i < 2; i++)
      stage16(gB + (size_t)(8 * i) * K, Bs + (w * 16 + 8 * i) * 64);
    __syncthreads();

#pragma unroll
    for (int hh = 0; hh < 2; hh++) {
      bf16x8 af[MR], bfv[2];
#pragma unroll
      for (int m = 0; m < MR; m++)
        af[m] = *reinterpret_cast<const bf16x8*>(
            As + (wr * (BM / 2) + m * 16 + l15) * 64 + hh * 32 + l4 * 8);
#pragma unroll
      for (int n = 0; n < 2; n++)
        bfv[n] = *reinterpret_cast<const bf16x8*>(
            Bs + (wc * 32 + n * 16 + l15) * 64 + hh * 32 + l4 * 8);
#pragma unroll
      for (int m = 0; m < MR; m++)
#pragma unroll
        for (int n = 0; n < 2; n++)
          acc[m][n] = __builtin_amdgcn_mfma_f32_16x16x32_bf16(af[m], bfv[n], acc[m][n], 0, 0, 0);
    }
    __syncthreads();
  }

  const int orow = row0 + wr * (BM / 2);
  const int ocol = col0 + wc * 32;
#pragma unroll
  for (int m = 0; m < MR; m++) {
#pragma unroll
    for (int n = 0; n < 2; n++) {
      const int c = ocol + n * 16 + l15;
#pragma unroll
      for (int j = 0; j < 4; j++) {
        const int r = orow + m * 16 + l4 * 4 + j;  // C/D: col=lane&15, row=(lane>>4)*4+reg
        const size_t idx2 = (size_t)r * N + c;
        const float v = acc[m][n][j];
        if (EPI == 0) {
          ((bf16*)Cout)[idx2] = (bf16)v;
        } else if (EPI == 1) {
          ((bf16*)Cout)[idx2] = (bf16)(((const float*)res)[idx2] + v);
        } else if (EPI == 2) {
          const float h = v + bias[c];
          ((bf16*)Cout)[idx2] = (bf16)(0.5f * h * (1.0f + erff(h * 0.70710678118f)));
        } else if (EPI == 3) {
          ((float*)Cout)[idx2] = (float)((const bf16*)res)[idx2] + v;
        } else {  // EPI == 4: kqv with Q pre-scale (log2-domain softmax)
          const float sc = (c >= 768 && c < 1536) ? 0.18033688011112042f : 1.0f;
          ((bf16*)Cout)[idx2] = (bf16)(v * sc);
        }
      }
    }
  }
}

// ------------------------------------------------------------------ attention
// kqv [T][2304] bf16 : k at +0, q at +768 (PRE-SCALED by 0.125*log2e),
// v at +1536, head offset h*64.
// Writes UNNORMALIZED partials: Opart[z][4096][768] bf16, Lpart[z][12][4096] f32.
// 768 blocks (NZ=2), XCD-swizzled 1D grid: each XCD owns 3 (h,z) slabs x
// 32 qb (KV slab L2-resident, R12 mechanism). bounds(256,3) + VGPR ~80:
// PROVEN LOCAL OPTIMUM (R14/R16 allocator gambles both regressed).
// No-max softmax (P = exp2(st), |st| << 127): partials EXACTLY additive.
// T5 setprio around compute phase (neutral-to-positive, R18).
//
// 32x32x16 MFMA: wave owns 32 q (q = lane&31). Block = 4 waves (QB=128);
// KV tile = 128, 16 iters. Swapped QK^T: S^T = mfma32(A=K, B=Q); C-layout
// col=lane&31=q, row = (reg&3) + 8*(reg>>2) + 4*hi (hi = lane>>5).
// Key-relabel (R9-verified): position p -> label
// L(p) = 32t + 16*(s4>>1) + 8*hi_p + (r4 + 4*(s4&1)) so the PV B-frag is
// lane-local AND LINEAR in reg order (pairs feed v_cvt_pk_bf16_f32).
// V scattered to Vt[d][L] at staging. lsum via ones-MFMA (accL[0] = full
// row sum). Bank-conflict-free via odd-16B strides (K 144B, Vt 272B).
// K/V reg-staged with cross-iteration prefetch.
__global__ __launch_bounds__(256, 3)
void attn_fused(const bf16* __restrict__ kqv,
                bf16* __restrict__ Opart,
                float* __restrict__ Lpart) {
  // XCD-aware decode: fid&7 = XCD slot; each XCD owns 3 (h,z) slabs x 32 qb.
  const int fid = blockIdx.x;
  const int xs = fid & 7, r = fid >> 3;
  const int qb = r & 31;
  const int s = xs * 3 + (r >> 5);  // 0..23
  const int h = s % 12, z = s / 12;
  const int tid = threadIdx.x, w = tid >> 6, lane = tid & 63;
  const int l31 = lane & 31, hi = lane >> 5;

  __shared__ __align__(16) char KsB[128 * 144];  // K [pos][64d], stride 144B
  __shared__ __align__(16) char VtB[64 * 272];   // V^T [d][128 labels], 272B

  // Q fragments (B operand): col=q=l31, k = hi*8 + e (+16 per frag)
  const int qrow = qb * 128 + w * 32 + l31;
  const bf16* qp = kqv + (size_t)qrow * 2304 + 768 + h * 64;
  bf16x8 qf[4];
#pragma unroll
  for (int m = 0; m < 4; m++)
    qf[m] = *reinterpret_cast<const bf16x8*>(qp + hi * 8 + 16 * m);

  bf16x8 ones;
#pragma unroll
  for (int e = 0; e < 8; e++) ones[e] = (bf16)1.0f;

  f32x16 accO0 = zero16(), accO1 = zero16(), accL = zero16();

  // K staging: row = tid>>1 (0..127), 64B half = tid&1 (4 b128 chunks)
  const int krow = tid >> 1;
  const int kc0 = (tid & 1) * 4;
  // V staging: keys kb*4..+3, d = db*8..+7; label base (bijective in kb):
  const int kb = tid & 31, db = tid >> 5;
  const int lb = ((kb >> 3) & 3) * 32 + ((kb >> 2) & 1) * 16 + (kb & 1) * 8 +
                 ((kb >> 1) & 1) * 4;

  const int kt0 = z * 16;  // this block's 16 key-tiles

  bf16x8 kreg[4], vreg[4];
#define LOADKV(kt)                                                               \
  {                                                                              \
    const bf16* kp =                                                             \
        kqv + (size_t)((kt)*128 + krow) * 2304 + h * 64 + kc0 * 8;               \
    _Pragma("unroll") for (int i = 0; i < 4; i++)                                \
        kreg[i] = *reinterpret_cast<const bf16x8*>(kp + i * 8);                  \
    const bf16* vp =                                                             \
        kqv + (size_t)((kt)*128 + kb * 4) * 2304 + 1536 + h * 64 + db * 8;       \
    _Pragma("unroll") for (int r2 = 0; r2 < 4; r2++)                             \
        vreg[r2] = *reinterpret_cast<const bf16x8*>(vp + (size_t)r2 * 2304);     \
  }

  LOADKV(kt0);

  for (int kt = 0; kt < 16; kt++) {
    __syncthreads();
    // ---- LDS writes from registers
    {
      char* kdst = KsB + krow * 144;
#pragma unroll
      for (int i = 0; i < 4; i++)
        *reinterpret_cast<bf16x8*>(kdst + ((kc0 + i) * 16)) = kreg[i];
#pragma unroll
      for (int e = 0; e < 8; e++) {
        const int d = db * 8 + e;
        const bf16x4 pk4 = (bf16x4){vreg[0][e], vreg[1][e], vreg[2][e], vreg[3][e]};
        *reinterpret_cast<bf16x4*>(VtB + d * 272 + lb * 2) = pk4;
      }
    }
    __syncthreads();
    if (kt + 1 < 16) LOADKV(kt0 + kt + 1);  // prefetch flies during compute

    __builtin_amdgcn_s_setprio(1);  // T5: favor compute-phase waves

    // ---- QK^T (4 pos-tiles of 32) -> exp2 -> pack (LINEAR pairs -> cvt_pk)
    bf16x8 pb[8];
#pragma unroll
    for (int t = 0; t < 4; t++) {
      f32x16 st = zero16();
#pragma unroll
      for (int m = 0; m < 4; m++) {
        const bf16x8 kf = *reinterpret_cast<const bf16x8*>(
            KsB + (size_t)(32 * t + l31) * 144 + (2 * m + hi) * 16);
        st = __builtin_amdgcn_mfma_f32_32x32x16_bf16(kf, qf[m], st, 0, 0, 0);
      }
#pragma unroll
      for (int hf = 0; hf < 2; hf++) {
        bf16x8 p;
#pragma unroll
        for (int j = 0; j < 8; j++) p[j] = (bf16)EXP2(st[hf * 8 + j]);
        pb[2 * t + hf] = p;
      }
    }

    // ---- O^T += V^T @ P^T ; accL += ones @ P^T (full row sum, matrix pipe)
#pragma unroll
    for (int mk = 0; mk < 8; mk++) {
      const bf16x8 vf0 = *reinterpret_cast<const bf16x8*>(
          VtB + (size_t)l31 * 272 + (2 * mk + hi) * 16);
      accO0 = __builtin_amdgcn_mfma_f32_32x32x16_bf16(vf0, pb[mk], accO0, 0, 0, 0);
      const bf16x8 vf1 = *reinterpret_cast<const bf16x8*>(
          VtB + (size_t)(32 + l31) * 272 + (2 * mk + hi) * 16);
      accO1 = __builtin_amdgcn_mfma_f32_32x32x16_bf16(vf1, pb[mk], accO1, 0, 0, 0);
      accL = __builtin_amdgcn_mfma_f32_32x32x16_bf16(ones, pb[mk], accL, 0, 0, 0);
    }

    __builtin_amdgcn_s_setprio(0);
  }
#undef LOADKV

  // ---- epilogue: write unnormalized bf16 partials
  // accO row d = 32*dt + (reg&3) + 8*(reg>>2) + 4*hi, col q = l31
  bf16* Oq = Opart + (size_t)z * T_SEQ * C_EMB + (size_t)qrow * C_EMB + h * 64;
#pragma unroll
  for (int s4 = 0; s4 < 4; s4++) {
    const bf16x4 o0 = (bf16x4){(bf16)accO0[4 * s4 + 0], (bf16)accO0[4 * s4 + 1],
                               (bf16)accO0[4 * s4 + 2], (bf16)accO0[4 * s4 + 3]};
    *reinterpret_cast<bf16x4*>(Oq + 8 * s4 + 4 * hi) = o0;
    const bf16x4 o1 = (bf16x4){(bf16)accO1[4 * s4 + 0], (bf16)accO1[4 * s4 + 1],
                               (bf16)accO1[4 * s4 + 2], (bf16)accO1[4 * s4 + 3]};
    *reinterpret_cast<bf16x4*>(Oq + 32 + 8 * s4 + 4 * hi) = o1;
  }
  // accL: every row of D equals the full row-sum; lane l31 holds col q=l31.
  if (hi == 0)
    Lpart[(size_t)z * NHEAD * T_SEQ + (size_t)h * T_SEQ + qrow] = accL[0];
}

// ------------------------------------------------------- attention combine
// out[q][c] = (sum_z Oz[q][c]) / (sum_z Lz[h][q]),  h = c/64
// Vectorized: bf16x8 loads/stores, 4 rows per 384-thread block.
__global__ void attn_combine(const bf16* __restrict__ Opart,
                             const float* __restrict__ Lpart,
                             bf16* __restrict__ out) {
  const int t = threadIdx.x;            // 384 = 4 rows x 96 chunks
  const int rr = t / 96, cc = t % 96;
  const int q = blockIdx.x * 4 + rr;
  const int c = cc * 8;
  const int h = c >> 6;
  float o[8];
#pragma unroll
  for (int j = 0; j < 8; j++) o[j] = 0.f;
  float L = 0.f;
#pragma unroll
  for (int z = 0; z < NZ; z++) {
    const bf16x8 v = *reinterpret_cast<const bf16x8*>(
        Opart + (size_t)z * T_SEQ * C_EMB + (size_t)q * C_EMB + c);
#pragma unroll
    for (int j = 0; j < 8; j++) o[j] += (float)v[j];
    L += Lpart[(size_t)z * NHEAD * T_SEQ + (size_t)h * T_SEQ + q];
  }
  const float inv = 1.0f / L;
  bf16x8 rv;
#pragma unroll
  for (int j = 0; j < 8; j++) rv[j] = (bf16)(o[j] * inv);
  *reinterpret_cast<bf16x8*>(out + (size_t)q * C_EMB + c) = rv;
}

// ------------------------------------------------------------------ launch
extern "C" void kernel_launch(void* const* d_in, const int* in_sizes, int n_in,
                              void* d_out, int out_size, void* d_ws, size_t ws_size,
                              hipStream_t stream) {
  const float* x       = (const float*)d_in[0];
  const float* W_kqv   = (const float*)d_in[1];
  const float* W_proj  = (const float*)d_in[2];
  const float* W_fc    = (const float*)d_in[3];
  const float* b_fc    = (const float*)d_in[4];
  const float* W_cproj = (const float*)d_in[5];
  float* outp = (float*)d_out;

  char* p = (char*)d_ws;
  bf16* Wkqv_t  = (bf16*)p; p += (size_t)2304 * 768 * 2;
  bf16* Wproj_t = (bf16*)p; p += (size_t)768 * 768 * 2;
  bf16* Wfc_t   = (bf16*)p; p += (size_t)1536 * 768 * 2;
  bf16* Wcp_t   = (bf16*)p; p += (size_t)768 * 1536 * 2;
  bf16* A1      = (bf16*)p; p += (size_t)4096 * 768 * 2;   // aliased: attn_out
  bf16* KQV     = (bf16*)p; p += (size_t)4096 * 2304 * 2;  // aliased: A2 | Hg
  bf16* x1      = (bf16*)p; p += (size_t)4096 * 768 * 2;   // bf16 residual
  bf16* Opart   = (bf16*)p; p += (size_t)NZ * 4096 * 768 * 2;
  float* Lpart  = (float*)p; p += (size_t)NZ * NHEAD * 4096 * 4;
  bf16* attn_o = A1;
  bf16* A2     = KQV;
  bf16* Hg     = KQV + (size_t)4096 * 768;

  // prep: all 4 weight transposes + LN1 in one launch (independent work)
  prep<<<8704, 256, 0, stream>>>(x, A1, W_kqv, Wkqv_t, W_proj, Wproj_t,
                                 W_fc, Wfc_t, W_cproj, Wcp_t);
  gemm_bt<4, 64><<<2304, 256, 0, stream>>>(A1, Wkqv_t, KQV, nullptr, nullptr,
                                           4096, 2304, 768);
  attn_fused<<<768, 256, 0, stream>>>(KQV, Opart, Lpart);
  attn_combine<<<1024, 384, 0, stream>>>(Opart, Lpart, attn_o);
  gemm_bt<1, 64><<<768, 256, 0, stream>>>(attn_o, Wproj_t, x1, x, nullptr,
                                          4096, 768, 768);
  ln_rows<<<1024, 256, 0, stream>>>(x1, A2);
  gemm_bt<2, 64><<<1536, 256, 0, stream>>>(A2, Wfc_t, Hg, nullptr, b_fc,
                                           4096, 1536, 768);
  gemm_bt<3, 64><<<768, 256, 0, stream>>>(Hg, Wcp_t, outp, x1, nullptr,
                                          4096, 768, 1536);
}

// Round 22
// 178.064 us; speedup vs baseline: 1.0206x; 1.0206x over previous
//
#include <hip/hip_runtime.h>
#include <hip/hip_bf16.h>
#include <math.h>

#define T_SEQ 4096
#define C_EMB 768
#define NHEAD 12
#define HDIM  64
#define NZ    2   // key-split (R19-proven)

typedef __bf16 bf16;
typedef __bf16 bf16x8 __attribute__((ext_vector_type(8)));
typedef __bf16 bf16x4 __attribute__((ext_vector_type(4)));
typedef float  f32x4  __attribute__((ext_vector_type(4)));
typedef float  f32x16 __attribute__((ext_vector_type(16)));

#if __has_builtin(__builtin_amdgcn_exp2f)
#define EXP2 __builtin_amdgcn_exp2f
#else
#define EXP2 exp2f
#endif

// ---------------------------------------------------------------- utilities

__device__ __forceinline__ void stage16(const void* g, void* ldsbase) {
  // global -> LDS direct, 16B per lane; LDS dest = wave-uniform base + lane*16
  __builtin_amdgcn_global_load_lds(
      (__attribute__((address_space(1))) const unsigned int*)g,
      (__attribute__((address_space(3))) unsigned int*)ldsbase, 16, 0, 0);
}

__device__ __forceinline__ f32x16 zero16() {
  f32x16 z;
#pragma unroll
  for (int i = 0; i < 16; i++) z[i] = 0.f;
  return z;
}

// ------------------------------------------------------------- prep kernel
// Fuses the 4 weight transposes (f32 [K][N] -> bf16 [N][K]) and the first
// layernorm into ONE launch (they are mutually independent).
__device__ __forceinline__ void do_transpose(const float* __restrict__ W,
                                             bf16* __restrict__ Wt, int K, int N,
                                             int bx, int by, int tid,
                                             float (*tile)[33]) {
  const int n0 = bx * 32, k0 = by * 32;
  const int tx = tid & 31, ty = tid >> 5;  // 256 thr: ty 0..7
#pragma unroll
  for (int i = 0; i < 32; i += 8)
    tile[ty + i][tx] = W[(size_t)(k0 + ty + i) * N + n0 + tx];
  __syncthreads();
#pragma unroll
  for (int i = 0; i < 32; i += 8)
    Wt[(size_t)(n0 + ty + i) * K + k0 + tx] = (bf16)tile[tx][ty + i];
}

__device__ __forceinline__ void do_ln(const float* __restrict__ x,
                                      bf16* __restrict__ y, int row, int t,
                                      float* red) {
  const float* xr = x + (size_t)row * C_EMB;
  float v0 = xr[t], v1 = xr[t + 256], v2 = xr[t + 512];
  float s  = v0 + v1 + v2;
  float ss = v0 * v0 + v1 * v1 + v2 * v2;
#pragma unroll
  for (int m = 1; m < 64; m <<= 1) {
    s += __shfl_xor(s, m);
    ss += __shfl_xor(ss, m);
  }
  const int w = t >> 6;
  if ((t & 63) == 0) { red[w] = s; red[4 + w] = ss; }
  __syncthreads();
  s  = red[0] + red[1] + red[2] + red[3];
  ss = red[4] + red[5] + red[6] + red[7];
  const float mu  = s * (1.0f / C_EMB);
  const float var = ss * (1.0f / C_EMB) - mu * mu;
  const float rs  = rsqrtf(var + 1e-5f);
  bf16* yr = y + (size_t)row * C_EMB;
  yr[t]       = (bf16)((v0 - mu) * rs);
  yr[t + 256] = (bf16)((v1 - mu) * rs);
  yr[t + 512] = (bf16)((v2 - mu) * rs);
}

__global__ void prep(const float* __restrict__ x, bf16* __restrict__ ln_out,
                     const float* __restrict__ W_kqv, bf16* __restrict__ Wkqv_t,
                     const float* __restrict__ W_proj, bf16* __restrict__ Wproj_t,
                     const float* __restrict__ W_fc, bf16* __restrict__ Wfc_t,
                     const float* __restrict__ W_cproj, bf16* __restrict__ Wcp_t) {
  __shared__ float tile[32][33];
  const int b = blockIdx.x, t = threadIdx.x;
  if (b < 1728) {
    do_transpose(W_kqv, Wkqv_t, 768, 2304, b % 72, b / 72, t, tile);
  } else if (b < 2304) {
    const int bb = b - 1728;
    do_transpose(W_proj, Wproj_t, 768, 768, bb % 24, bb / 24, t, tile);
  } else if (b < 3456) {
    const int bb = b - 2304;
    do_transpose(W_fc, Wfc_t, 768, 1536, bb % 48, bb / 48, t, tile);
  } else if (b < 4608) {
    const int bb = b - 3456;
    do_transpose(W_cproj, Wcp_t, 1536, 768, bb % 24, bb / 24, t, tile);
  } else {
    do_ln(x, ln_out, b - 4608, t, &tile[0][0]);
  }
}

// ------------------------------------------------------------------ layernorm2
// x1 [4096][768] bf16 -> y bf16. Wave-per-row (no LDS, no syncthreads):
// lane owns 12 elems (bf16x8 @ l*8 + bf16x4 @ 512+l*4), shfl_xor reduce.
// 4 rows per 256-thread block.
__global__ void ln_rows(const bf16* __restrict__ x, bf16* __restrict__ y) {
  const int w = threadIdx.x >> 6, l = threadIdx.x & 63;
  const int row = blockIdx.x * 4 + w;
  const bf16* xr = x + (size_t)row * C_EMB;
  const bf16x8 v8 = *reinterpret_cast<const bf16x8*>(xr + l * 8);
  const bf16x4 v4 = *reinterpret_cast<const bf16x4*>(xr + 512 + l * 4);
  float f[12];
#pragma unroll
  for (int j = 0; j < 8; j++) f[j] = (float)v8[j];
#pragma unroll
  for (int j = 0; j < 4; j++) f[8 + j] = (float)v4[j];
  float s = 0.f, ss = 0.f;
#pragma unroll
  for (int j = 0; j < 12; j++) { s += f[j]; ss += f[j] * f[j]; }
#pragma unroll
  for (int m = 1; m < 64; m <<= 1) {
    s += __shfl_xor(s, m);
    ss += __shfl_xor(ss, m);
  }
  const float mu  = s * (1.0f / C_EMB);
  const float var = ss * (1.0f / C_EMB) - mu * mu;
  const float rs  = rsqrtf(var + 1e-5f);
  bf16x8 o8;
  bf16x4 o4;
#pragma unroll
  for (int j = 0; j < 8; j++) o8[j] = (bf16)((f[j] - mu) * rs);
#pragma unroll
  for (int j = 0; j < 4; j++) o4[j] = (bf16)((f[8 + j] - mu) * rs);
  bf16* yr = y + (size_t)row * C_EMB;
  *reinterpret_cast<bf16x8*>(yr + l * 8) = o8;
  *reinterpret_cast<bf16x4*>(yr + 512 + l * 4) = o4;
}

// ------------------------------------------------------------------ GEMM
// C[M][N] = A[M][K](bf16 rowmajor) x BT[N][K](bf16)   (i.e. A @ B)
// Single-buffer m97 pattern, BK=64, BN=64. Template BM in {64,128}:
// BM=64 for proj/fc/cproj (latency-bound, want blocks: R20 win); BM=128 for
// kqv (4.5 blocks/CU already; BM=64 regressed it, R21 -- boundary mapped).
// Wave = (BM/2)x32, acc (BM/32)x2. XCD-aware 1D grid (bijective, nrow%8==0).
// EPI 0: store bf16                  EPI 1: bf16 = res_f32 + acc  (x1 resid)
// EPI 2: bf16 = gelu(acc + bias[c])  EPI 3: f32 = res_bf16 + acc  (output)
// EPI 4: bf16 store, cols [768,1536) scaled by 0.125*log2e (kqv Q pre-scale)
template <int EPI, int BM>
__global__ void gemm_bt(const bf16* __restrict__ A, const bf16* __restrict__ BT,
                        void* __restrict__ Cout, const void* __restrict__ res,
                        const float* __restrict__ bias, int M, int N, int K) {
  __shared__ __align__(16) bf16 As[BM * 64];
  __shared__ __align__(16) bf16 Bs[64 * 64];
  constexpr int MR = BM / 32;           // A fragments (rows of 16) per wave
  // ---- XCD-aware decode: xcd = bid&7 owns nrow/8 row-panels x all cols
  const int nrow = M / BM;
  const int ncol = N >> 6;
  const int rpx = nrow >> 3;
  const int bid = blockIdx.x;
  const int xcd = bid & 7, idx = bid >> 3;
  const int rowb = xcd * rpx + idx / ncol;
  const int colb = idx % ncol;
  const int row0 = rowb * BM, col0 = colb * 64;

  const int tid = threadIdx.x;
  const int w = tid >> 6, lane = tid & 63;
  const int wr = w >> 1, wc = w & 1;
  const int l15 = lane & 15, l4 = lane >> 4;

  f32x4 acc[MR][2];
#pragma unroll
  for (int m = 0; m < MR; m++)
#pragma unroll
    for (int n = 0; n < 2; n++) acc[m][n] = (f32x4){0.f, 0.f, 0.f, 0.f};

  const int rr = lane >> 3;        // 8 rows per 1KB wave-instr (128B rows)
  const int c8 = (lane & 7) * 8;   // 8 chunks of 8 bf16 per 128B row

  for (int k0 = 0; k0 < K; k0 += 64) {
    const bf16* gA = A + (size_t)(row0 + w * (BM / 4) + rr) * K + k0 + c8;
    const bf16* gB = BT + (size_t)(col0 + w * 16 + rr) * K + k0 + c8;
#pragma unroll
    for (int i = 0; i < BM / 32; i++)
      stage16(gA + (size_t)(8 * i) * K, As + (w * (BM / 4) + 8 * i) * 64);
#pragma unroll
    for (int i = 0; i < 2; i++)
      stage16(gB + (size_t)(8 * i) * K, Bs + (w * 16 + 8 * i) * 64);
    __syncthreads();

#pragma unroll
    for (int hh = 0; hh < 2; hh++) {
      bf16x8 af[MR], bfv[2];
#pragma unroll
      for (int m = 0; m < MR; m++)
        af[m] = *reinterpret_cast<const bf16x8*>(
            As + (wr * (BM / 2) + m * 16 + l15) * 64 + hh * 32 + l4 * 8);
#pragma unroll
      for (int n = 0; n < 2; n++)
        bfv[n] = *reinterpret_cast<const bf16x8*>(
            Bs + (wc * 32 + n * 16 + l15) * 64 + hh * 32 + l4 * 8);
#pragma unroll
      for (int m = 0; m < MR; m++)
#pragma unroll
        for (int n = 0; n < 2; n++)
          acc[m][n] = __builtin_amdgcn_mfma_f32_16x16x32_bf16(af[m], bfv[n], acc[m][n], 0, 0, 0);
    }
    __syncthreads();
  }

  const int orow = row0 + wr * (BM / 2);
  const int ocol = col0 + wc * 32;
#pragma unroll
  for (int m = 0; m < MR; m++) {
#pragma unroll
    for (int n = 0; n < 2; n++) {
      const int c = ocol + n * 16 + l15;
#pragma unroll
      for (int j = 0; j < 4; j++) {
        const int r = orow + m * 16 + l4 * 4 + j;  // C/D: col=lane&15, row=(lane>>4)*4+reg
        const size_t idx2 = (size_t)r * N + c;
        const float v = acc[m][n][j];
        if (EPI == 0) {
          ((bf16*)Cout)[idx2] = (bf16)v;
        } else if (EPI == 1) {
          ((bf16*)Cout)[idx2] = (bf16)(((const float*)res)[idx2] + v);
        } else if (EPI == 2) {
          const float h = v + bias[c];
          ((bf16*)Cout)[idx2] = (bf16)(0.5f * h * (1.0f + erff(h * 0.70710678118f)));
        } else if (EPI == 3) {
          ((float*)Cout)[idx2] = (float)((const bf16*)res)[idx2] + v;
        } else {  // EPI == 4: kqv with Q pre-scale (log2-domain softmax)
          const float sc = (c >= 768 && c < 1536) ? 0.18033688011112042f : 1.0f;
          ((bf16*)Cout)[idx2] = (bf16)(v * sc);
        }
      }
    }
  }
}

// ------------------------------------------------------------------ attention
// kqv [T][2304] bf16 : k at +0, q at +768 (PRE-SCALED by 0.125*log2e),
// v at +1536, head offset h*64.
// Writes UNNORMALIZED partials: Opart[z][4096][768] bf16, Lpart[z][12][4096] f32.
// 768 blocks (NZ=2), XCD-swizzled 1D grid: each XCD owns 3 (h,z) slabs x
// 32 qb (KV slab L2-resident, R12 mechanism). bounds(256,3) + VGPR ~80:
// PROVEN LOCAL OPTIMUM (R14/R16 allocator gambles both regressed).
// No-max softmax (P = exp2(st), |st| << 127): partials EXACTLY additive.
// T5 setprio around compute phase (neutral-to-positive, R18).
//
// 32x32x16 MFMA: wave owns 32 q (q = lane&31). Block = 4 waves (QB=128);
// KV tile = 128, 16 iters. Swapped QK^T: S^T = mfma32(A=K, B=Q); C-layout
// col=lane&31=q, row = (reg&3) + 8*(reg>>2) + 4*hi (hi = lane>>5).
// Key-relabel (R9-verified): position p -> label
// L(p) = 32t + 16*(s4>>1) + 8*hi_p + (r4 + 4*(s4&1)) so the PV B-frag is
// lane-local AND LINEAR in reg order (pairs feed v_cvt_pk_bf16_f32).
// V scattered to Vt[d][L] at staging. lsum via ones-MFMA (accL[0] = full
// row sum). Bank-conflict-free via odd-16B strides (K 144B, Vt 272B).
// K/V reg-staged with cross-iteration prefetch.
__global__ __launch_bounds__(256, 3)
void attn_fused(const bf16* __restrict__ kqv,
                bf16* __restrict__ Opart,
                float* __restrict__ Lpart) {
  // XCD-aware decode: fid&7 = XCD slot; each XCD owns 3 (h,z) slabs x 32 qb.
  const int fid = blockIdx.x;
  const int xs = fid & 7, r = fid >> 3;
  const int qb = r & 31;
  const int s = xs * 3 + (r >> 5);  // 0..23
  const int h = s % 12, z = s / 12;
  const int tid = threadIdx.x, w = tid >> 6, lane = tid & 63;
  const int l31 = lane & 31, hi = lane >> 5;

  __shared__ __align__(16) char KsB[128 * 144];  // K [pos][64d], stride 144B
  __shared__ __align__(16) char VtB[64 * 272];   // V^T [d][128 labels], 272B

  // Q fragments (B operand): col=q=l31, k = hi*8 + e (+16 per frag)
  const int qrow = qb * 128 + w * 32 + l31;
  const bf16* qp = kqv + (size_t)qrow * 2304 + 768 + h * 64;
  bf16x8 qf[4];
#pragma unroll
  for (int m = 0; m < 4; m++)
    qf[m] = *reinterpret_cast<const bf16x8*>(qp + hi * 8 + 16 * m);

  bf16x8 ones;
#pragma unroll
  for (int e = 0; e < 8; e++) ones[e] = (bf16)1.0f;

  f32x16 accO0 = zero16(), accO1 = zero16(), accL = zero16();

  // K staging: row = tid>>1 (0..127), 64B half = tid&1 (4 b128 chunks)
  const int krow = tid >> 1;
  const int kc0 = (tid & 1) * 4;
  // V staging: keys kb*4..+3, d = db*8..+7; label base (bijective in kb):
  const int kb = tid & 31, db = tid >> 5;
  const int lb = ((kb >> 3) & 3) * 32 + ((kb >> 2) & 1) * 16 + (kb & 1) * 8 +
                 ((kb >> 1) & 1) * 4;

  const int kt0 = z * 16;  // this block's 16 key-tiles

  bf16x8 kreg[4], vreg[4];
#define LOADKV(kt)                                                               \
  {                                                                              \
    const bf16* kp =                                                             \
        kqv + (size_t)((kt)*128 + krow) * 2304 + h * 64 + kc0 * 8;               \
    _Pragma("unroll") for (int i = 0; i < 4; i++)                                \
        kreg[i] = *reinterpret_cast<const bf16x8*>(kp + i * 8);                  \
    const bf16* vp =                                                             \
        kqv + (size_t)((kt)*128 + kb * 4) * 2304 + 1536 + h * 64 + db * 8;       \
    _Pragma("unroll") for (int r2 = 0; r2 < 4; r2++)                             \
        vreg[r2] = *reinterpret_cast<const bf16x8*>(vp + (size_t)r2 * 2304);     \
  }

  LOADKV(kt0);

  for (int kt = 0; kt < 16; kt++) {
    __syncthreads();
    // ---- LDS writes from registers
    {
      char* kdst = KsB + krow * 144;
#pragma unroll
      for (int i = 0; i < 4; i++)
        *reinterpret_cast<bf16x8*>(kdst + ((kc0 + i) * 16)) = kreg[i];
#pragma unroll
      for (int e = 0; e < 8; e++) {
        const int d = db * 8 + e;
        const bf16x4 pk4 = (bf16x4){vreg[0][e], vreg[1][e], vreg[2][e], vreg[3][e]};
        *reinterpret_cast<bf16x4*>(VtB + d * 272 + lb * 2) = pk4;
      }
    }
    __syncthreads();
    if (kt + 1 < 16) LOADKV(kt0 + kt + 1);  // prefetch flies during compute

    __builtin_amdgcn_s_setprio(1);  // T5: favor compute-phase waves

    // ---- QK^T (4 pos-tiles of 32) -> exp2 -> pack (LINEAR pairs -> cvt_pk)
    bf16x8 pb[8];
#pragma unroll
    for (int t = 0; t < 4; t++) {
      f32x16 st = zero16();
#pragma unroll
      for (int m = 0; m < 4; m++) {
        const bf16x8 kf = *reinterpret_cast<const bf16x8*>(
            KsB + (size_t)(32 * t + l31) * 144 + (2 * m + hi) * 16);
        st = __builtin_amdgcn_mfma_f32_32x32x16_bf16(kf, qf[m], st, 0, 0, 0);
      }
#pragma unroll
      for (int hf = 0; hf < 2; hf++) {
        bf16x8 p;
#pragma unroll
        for (int j = 0; j < 8; j++) p[j] = (bf16)EXP2(st[hf * 8 + j]);
        pb[2 * t + hf] = p;
      }
    }

    // ---- O^T += V^T @ P^T ; accL += ones @ P^T (full row sum, matrix pipe)
#pragma unroll
    for (int mk = 0; mk < 8; mk++) {
      const bf16x8 vf0 = *reinterpret_cast<const bf16x8*>(
          VtB + (size_t)l31 * 272 + (2 * mk + hi) * 16);
      accO0 = __builtin_amdgcn_mfma_f32_32x32x16_bf16(vf0, pb[mk], accO0, 0, 0, 0);
      const bf16x8 vf1 = *reinterpret_cast<const bf16x8*>(
          VtB + (size_t)(32 + l31) * 272 + (2 * mk + hi) * 16);
      accO1 = __builtin_amdgcn_mfma_f32_32x32x16_bf16(vf1, pb[mk], accO1, 0, 0, 0);
      accL = __builtin_amdgcn_mfma_f32_32x32x16_bf16(ones, pb[mk], accL, 0, 0, 0);
    }

    __builtin_amdgcn_s_setprio(0);
  }
#undef LOADKV

  // ---- epilogue: write unnormalized bf16 partials
  // accO row d = 32*dt + (reg&3) + 8*(reg>>2) + 4*hi, col q = l31
  bf16* Oq = Opart + (size_t)z * T_SEQ * C_EMB + (size_t)qrow * C_EMB + h * 64;
#pragma unroll
  for (int s4 = 0; s4 < 4; s4++) {
    const bf16x4 o0 = (bf16x4){(bf16)accO0[4 * s4 + 0], (bf16)accO0[4 * s4 + 1],
                               (bf16)accO0[4 * s4 + 2], (bf16)accO0[4 * s4 + 3]};
    *reinterpret_cast<bf16x4*>(Oq + 8 * s4 + 4 * hi) = o0;
    const bf16x4 o1 = (bf16x4){(bf16)accO1[4 * s4 + 0], (bf16)accO1[4 * s4 + 1],
                               (bf16)accO1[4 * s4 + 2], (bf16)accO1[4 * s4 + 3]};
    *reinterpret_cast<bf16x4*>(Oq + 32 + 8 * s4 + 4 * hi) = o1;
  }
  // accL: every row of D equals the full row-sum; lane l31 holds col q=l31.
  if (hi == 0)
    Lpart[(size_t)z * NHEAD * T_SEQ + (size_t)h * T_SEQ + qrow] = accL[0];
}

// ------------------------------------------------------- attention combine
// out[q][c] = (sum_z Oz[q][c]) / (sum_z Lz[h][q]),  h = c/64
// Vectorized: bf16x8 loads/stores, 4 rows per 384-thread block.
__global__ void attn_combine(const bf16* __restrict__ Opart,
                             const float* __restrict__ Lpart,
                             bf16* __restrict__ out) {
  const int t = threadIdx.x;            // 384 = 4 rows x 96 chunks
  const int rr = t / 96, cc = t % 96;
  const int q = blockIdx.x * 4 + rr;
  const int c = cc * 8;
  const int h = c >> 6;
  float o[8];
#pragma unroll
  for (int j = 0; j < 8; j++) o[j] = 0.f;
  float L = 0.f;
#pragma unroll
  for (int z = 0; z < NZ; z++) {
    const bf16x8 v = *reinterpret_cast<const bf16x8*>(
        Opart + (size_t)z * T_SEQ * C_EMB + (size_t)q * C_EMB + c);
#pragma unroll
    for (int j = 0; j < 8; j++) o[j] += (float)v[j];
    L += Lpart[(size_t)z * NHEAD * T_SEQ + (size_t)h * T_SEQ + q];
  }
  const float inv = 1.0f / L;
  bf16x8 rv;
#pragma unroll
  for (int j = 0; j < 8; j++) rv[j] = (bf16)(o[j] * inv);
  *reinterpret_cast<bf16x8*>(out + (size_t)q * C_EMB + c) = rv;
}

// ------------------------------------------------------------------ launch
extern "C" void kernel_launch(void* const* d_in, const int* in_sizes, int n_in,
                              void* d_out, int out_size, void* d_ws, size_t ws_size,
                              hipStream_t stream) {
  const float* x       = (const float*)d_in[0];
  const float* W_kqv   = (const float*)d_in[1];
  const float* W_proj  = (const float*)d_in[2];
  const float* W_fc    = (const float*)d_in[3];
  const float* b_fc    = (const float*)d_in[4];
  const float* W_cproj = (const float*)d_in[5];
  float* outp = (float*)d_out;

  char* p = (char*)d_ws;
  bf16* Wkqv_t  = (bf16*)p; p += (size_t)2304 * 768 * 2;
  bf16* Wproj_t = (bf16*)p; p += (size_t)768 * 768 * 2;
  bf16* Wfc_t   = (bf16*)p; p += (size_t)1536 * 768 * 2;
  bf16* Wcp_t   = (bf16*)p; p += (size_t)768 * 1536 * 2;
  bf16* A1      = (bf16*)p; p += (size_t)4096 * 768 * 2;   // aliased: attn_out
  bf16* KQV     = (bf16*)p; p += (size_t)4096 * 2304 * 2;  // aliased: A2 | Hg
  bf16* x1      = (bf16*)p; p += (size_t)4096 * 768 * 2;   // bf16 residual
  bf16* Opart   = (bf16*)p; p += (size_t)NZ * 4096 * 768 * 2;
  float* Lpart  = (float*)p; p += (size_t)NZ * NHEAD * 4096 * 4;
  bf16* attn_o = A1;
  bf16* A2     = KQV;
  bf16* Hg     = KQV + (size_t)4096 * 768;

  // prep: all 4 weight transposes + LN1 in one launch (independent work)
  prep<<<8704, 256, 0, stream>>>(x, A1, W_kqv, Wkqv_t, W_proj, Wproj_t,
                                 W_fc, Wfc_t, W_cproj, Wcp_t);
  gemm_bt<4, 128><<<1152, 256, 0, stream>>>(A1, Wkqv_t, KQV, nullptr, nullptr,
                                            4096, 2304, 768);
  attn_fused<<<768, 256, 0, stream>>>(KQV, Opart, Lpart);
  attn_combine<<<1024, 384, 0, stream>>>(Opart, Lpart, attn_o);
  gemm_bt<1, 64><<<768, 256, 0, stream>>>(attn_o, Wproj_t, x1, x, nullptr,
                                          4096, 768, 768);
  ln_rows<<<1024, 256, 0, stream>>>(x1, A2);
  gemm_bt<2, 64><<<1536, 256, 0, stream>>>(A2, Wfc_t, Hg, nullptr, b_fc,
                                           4096, 1536, 768);
  gemm_bt<3, 64><<<768, 256, 0, stream>>>(Hg, Wcp_t, outp, x1, nullptr,
                                          4096, 768, 1536);
}

// Round 23
// 178.031 us; speedup vs baseline: 1.0207x; 1.0002x over previous
//
#include <hip/hip_runtime.h>
#include <hip/hip_bf16.h>
#include <math.h>

#define T_SEQ 4096
#define C_EMB 768
#define NHEAD 12
#define HDIM  64
#define NZ    2   // key-split (R19-proven)

typedef __bf16 bf16;
typedef __bf16 bf16x8 __attribute__((ext_vector_type(8)));
typedef __bf16 bf16x4 __attribute__((ext_vector_type(4)));
typedef float  f32x4  __attribute__((ext_vector_type(4)));
typedef float  f32x16 __attribute__((ext_vector_type(16)));

#if __has_builtin(__builtin_amdgcn_exp2f)
#define EXP2 __builtin_amdgcn_exp2f
#else
#define EXP2 exp2f
#endif

// ---------------------------------------------------------------- utilities

__device__ __forceinline__ void stage16(const void* g, void* ldsbase) {
  // global -> LDS direct, 16B per lane; LDS dest = wave-uniform base + lane*16
  __builtin_amdgcn_global_load_lds(
      (__attribute__((address_space(1))) const unsigned int*)g,
      (__attribute__((address_space(3))) unsigned int*)ldsbase, 16, 0, 0);
}

__device__ __forceinline__ f32x16 zero16() {
  f32x16 z;
#pragma unroll
  for (int i = 0; i < 16; i++) z[i] = 0.f;
  return z;
}

// ------------------------------------------------------------- prep kernel
// Fuses the 4 weight transposes (f32 [K][N] -> bf16 [N][K]) and the first
// layernorm into ONE launch (they are mutually independent).
__device__ __forceinline__ void do_transpose(const float* __restrict__ W,
                                             bf16* __restrict__ Wt, int K, int N,
                                             int bx, int by, int tid,
                                             float (*tile)[33]) {
  const int n0 = bx * 32, k0 = by * 32;
  const int tx = tid & 31, ty = tid >> 5;  // 256 thr: ty 0..7
#pragma unroll
  for (int i = 0; i < 32; i += 8)
    tile[ty + i][tx] = W[(size_t)(k0 + ty + i) * N + n0 + tx];
  __syncthreads();
#pragma unroll
  for (int i = 0; i < 32; i += 8)
    Wt[(size_t)(n0 + ty + i) * K + k0 + tx] = (bf16)tile[tx][ty + i];
}

__device__ __forceinline__ void do_ln(const float* __restrict__ x,
                                      bf16* __restrict__ y, int row, int t,
                                      float* red) {
  const float* xr = x + (size_t)row * C_EMB;
  float v0 = xr[t], v1 = xr[t + 256], v2 = xr[t + 512];
  float s  = v0 + v1 + v2;
  float ss = v0 * v0 + v1 * v1 + v2 * v2;
#pragma unroll
  for (int m = 1; m < 64; m <<= 1) {
    s += __shfl_xor(s, m);
    ss += __shfl_xor(ss, m);
  }
  const int w = t >> 6;
  if ((t & 63) == 0) { red[w] = s; red[4 + w] = ss; }
  __syncthreads();
  s  = red[0] + red[1] + red[2] + red[3];
  ss = red[4] + red[5] + red[6] + red[7];
  const float mu  = s * (1.0f / C_EMB);
  const float var = ss * (1.0f / C_EMB) - mu * mu;
  const float rs  = rsqrtf(var + 1e-5f);
  bf16* yr = y + (size_t)row * C_EMB;
  yr[t]       = (bf16)((v0 - mu) * rs);
  yr[t + 256] = (bf16)((v1 - mu) * rs);
  yr[t + 512] = (bf16)((v2 - mu) * rs);
}

__global__ void prep(const float* __restrict__ x, bf16* __restrict__ ln_out,
                     const float* __restrict__ W_kqv, bf16* __restrict__ Wkqv_t,
                     const float* __restrict__ W_proj, bf16* __restrict__ Wproj_t,
                     const float* __restrict__ W_fc, bf16* __restrict__ Wfc_t,
                     const float* __restrict__ W_cproj, bf16* __restrict__ Wcp_t) {
  __shared__ float tile[32][33];
  const int b = blockIdx.x, t = threadIdx.x;
  if (b < 1728) {
    do_transpose(W_kqv, Wkqv_t, 768, 2304, b % 72, b / 72, t, tile);
  } else if (b < 2304) {
    const int bb = b - 1728;
    do_transpose(W_proj, Wproj_t, 768, 768, bb % 24, bb / 24, t, tile);
  } else if (b < 3456) {
    const int bb = b - 2304;
    do_transpose(W_fc, Wfc_t, 768, 1536, bb % 48, bb / 48, t, tile);
  } else if (b < 4608) {
    const int bb = b - 3456;
    do_transpose(W_cproj, Wcp_t, 1536, 768, bb % 24, bb / 24, t, tile);
  } else {
    do_ln(x, ln_out, b - 4608, t, &tile[0][0]);
  }
}

// ------------------------------------------------------------------ layernorm2
// x1 [4096][768] bf16 -> y bf16. Wave-per-row (no LDS, no syncthreads):
// lane owns 12 elems (bf16x8 @ l*8 + bf16x4 @ 512+l*4), shfl_xor reduce.
// 4 rows per 256-thread block.
__global__ void ln_rows(const bf16* __restrict__ x, bf16* __restrict__ y) {
  const int w = threadIdx.x >> 6, l = threadIdx.x & 63;
  const int row = blockIdx.x * 4 + w;
  const bf16* xr = x + (size_t)row * C_EMB;
  const bf16x8 v8 = *reinterpret_cast<const bf16x8*>(xr + l * 8);
  const bf16x4 v4 = *reinterpret_cast<const bf16x4*>(xr + 512 + l * 4);
  float f[12];
#pragma unroll
  for (int j = 0; j < 8; j++) f[j] = (float)v8[j];
#pragma unroll
  for (int j = 0; j < 4; j++) f[8 + j] = (float)v4[j];
  float s = 0.f, ss = 0.f;
#pragma unroll
  for (int j = 0; j < 12; j++) { s += f[j]; ss += f[j] * f[j]; }
#pragma unroll
  for (int m = 1; m < 64; m <<= 1) {
    s += __shfl_xor(s, m);
    ss += __shfl_xor(ss, m);
  }
  const float mu  = s * (1.0f / C_EMB);
  const float var = ss * (1.0f / C_EMB) - mu * mu;
  const float rs  = rsqrtf(var + 1e-5f);
  bf16x8 o8;
  bf16x4 o4;
#pragma unroll
  for (int j = 0; j < 8; j++) o8[j] = (bf16)((f[j] - mu) * rs);
#pragma unroll
  for (int j = 0; j < 4; j++) o4[j] = (bf16)((f[8 + j] - mu) * rs);
  bf16* yr = y + (size_t)row * C_EMB;
  *reinterpret_cast<bf16x8*>(yr + l * 8) = o8;
  *reinterpret_cast<bf16x4*>(yr + 512 + l * 4) = o4;
}

// ------------------------------------------------------------------ GEMM
// C[M][N] = A[M][K](bf16 rowmajor) x BT[N][K](bf16)   (i.e. A @ B)
// Single-buffer m97 pattern, BK=64, BN=64. Template BM in {64,128}:
// BM=64 for fc/cproj (latency-bound, want blocks: R20 win); BM=128 for
// kqv (4.5 blocks/CU already; BM=64 regressed it, R21 -- boundary mapped).
// Wave = (BM/2)x32, acc (BM/32)x2. XCD-aware 1D grid (bijective, nrow%8==0).
// EPI 0: store bf16                  EPI 2: bf16 = gelu(acc + bias[c])
// EPI 3: f32 = res_bf16 + acc        EPI 4: bf16 store, cols [768,1536)
//        scaled by 0.125*log2e (kqv Q pre-scale)
template <int EPI, int BM>
__global__ void gemm_bt(const bf16* __restrict__ A, const bf16* __restrict__ BT,
                        void* __restrict__ Cout, const void* __restrict__ res,
                        const float* __restrict__ bias, int M, int N, int K) {
  __shared__ __align__(16) bf16 As[BM * 64];
  __shared__ __align__(16) bf16 Bs[64 * 64];
  constexpr int MR = BM / 32;           // A fragments (rows of 16) per wave
  // ---- XCD-aware decode: xcd = bid&7 owns nrow/8 row-panels x all cols
  const int nrow = M / BM;
  const int ncol = N >> 6;
  const int rpx = nrow >> 3;
  const int bid = blockIdx.x;
  const int xcd = bid & 7, idx = bid >> 3;
  const int rowb = xcd * rpx + idx / ncol;
  const int colb = idx % ncol;
  const int row0 = rowb * BM, col0 = colb * 64;

  const int tid = threadIdx.x;
  const int w = tid >> 6, lane = tid & 63;
  const int wr = w >> 1, wc = w & 1;
  const int l15 = lane & 15, l4 = lane >> 4;

  f32x4 acc[MR][2];
#pragma unroll
  for (int m = 0; m < MR; m++)
#pragma unroll
    for (int n = 0; n < 2; n++) acc[m][n] = (f32x4){0.f, 0.f, 0.f, 0.f};

  const int rr = lane >> 3;        // 8 rows per 1KB wave-instr (128B rows)
  const int c8 = (lane & 7) * 8;   // 8 chunks of 8 bf16 per 128B row

  for (int k0 = 0; k0 < K; k0 += 64) {
    const bf16* gA = A + (size_t)(row0 + w * (BM / 4) + rr) * K + k0 + c8;
    const bf16* gB = BT + (size_t)(col0 + w * 16 + rr) * K + k0 + c8;
#pragma unroll
    for (int i = 0; i < BM / 32; i++)
      stage16(gA + (size_t)(8 * i) * K, As + (w * (BM / 4) + 8 * i) * 64);
#pragma unroll
    for (int i = 0; i < 2; i++)
      stage16(gB + (size_t)(8 * i) * K, Bs + (w * 16 + 8 * i) * 64);
    __syncthreads();

#pragma unroll
    for (int hh = 0; hh < 2; hh++) {
      bf16x8 af[MR], bfv[2];
#pragma unroll
      for (int m = 0; m < MR; m++)
        af[m] = *reinterpret_cast<const bf16x8*>(
            As + (wr * (BM / 2) + m * 16 + l15) * 64 + hh * 32 + l4 * 8);
#pragma unroll
      for (int n = 0; n < 2; n++)
        bfv[n] = *reinterpret_cast<const bf16x8*>(
            Bs + (wc * 32 + n * 16 + l15) * 64 + hh * 32 + l4 * 8);
#pragma unroll
      for (int m = 0; m < MR; m++)
#pragma unroll
        for (int n = 0; n < 2; n++)
          acc[m][n] = __builtin_amdgcn_mfma_f32_16x16x32_bf16(af[m], bfv[n], acc[m][n], 0, 0, 0);
    }
    __syncthreads();
  }

  const int orow = row0 + wr * (BM / 2);
  const int ocol = col0 + wc * 32;
#pragma unroll
  for (int m = 0; m < MR; m++) {
#pragma unroll
    for (int n = 0; n < 2; n++) {
      const int c = ocol + n * 16 + l15;
#pragma unroll
      for (int j = 0; j < 4; j++) {
        const int r = orow + m * 16 + l4 * 4 + j;  // C/D: col=lane&15, row=(lane>>4)*4+reg
        const size_t idx2 = (size_t)r * N + c;
        const float v = acc[m][n][j];
        if (EPI == 0) {
          ((bf16*)Cout)[idx2] = (bf16)v;
        } else if (EPI == 2) {
          const float h = v + bias[c];
          ((bf16*)Cout)[idx2] = (bf16)(0.5f * h * (1.0f + erff(h * 0.70710678118f)));
        } else if (EPI == 3) {
          ((float*)Cout)[idx2] = (float)((const bf16*)res)[idx2] + v;
        } else {  // EPI == 4: kqv with Q pre-scale (log2-domain softmax)
          const float sc = (c >= 768 && c < 1536) ? 0.18033688011112042f : 1.0f;
          ((bf16*)Cout)[idx2] = (bf16)(v * sc);
        }
      }
    }
  }
}

// ------------------------------------------------------- proj GEMM + combine
// x1[M][768] bf16 = x_f32 + ((Opart0 + Opart1)/L) @ Wproj.
// Clone of gemm_bt<1,64> with the attention-combine FUSED into the A-staging:
// BK=64 == HDIM, so h = k0>>6 is uniform per K-step and the normalizer
// L = L0[h][row]+L1[h][row] is one scalar per staged row. A is reg-staged
// (load both z-partials, add, scale, one bf16 round -- BIT-IDENTICAL to the
// old combine kernel -- then ds_write_b128). B keeps global_load_lds.
// Deletes the combine kernel + the attn_o write/read round-trip (12 MB).
__global__ void gemm_proj(const bf16* __restrict__ Opart,
                          const float* __restrict__ Lpart,
                          const bf16* __restrict__ BT,
                          bf16* __restrict__ Cout,
                          const float* __restrict__ res) {
  constexpr int M = 4096, N = 768, K = 768;
  __shared__ __align__(16) bf16 As[64 * 64];
  __shared__ __align__(16) bf16 Bs[64 * 64];
  // XCD decode: nrow = 64, ncol = 12, rpx = 8
  const int bid = blockIdx.x;
  const int xcd = bid & 7, idx = bid >> 3;
  const int rowb = xcd * 8 + idx / 12;
  const int colb = idx % 12;
  const int row0 = rowb * 64, col0 = colb * 64;

  const int tid = threadIdx.x;
  const int w = tid >> 6, lane = tid & 63;
  const int wr = w >> 1, wc = w & 1;
  const int l15 = lane & 15, l4 = lane >> 4;

  f32x4 acc[2][2];
#pragma unroll
  for (int m = 0; m < 2; m++)
#pragma unroll
    for (int n = 0; n < 2; n++) acc[m][n] = (f32x4){0.f, 0.f, 0.f, 0.f};

  const int rr = lane >> 3;        // 8 rows per 1KB wave-instr
  const int c8 = (lane & 7) * 8;   // 8-bf16 chunk within the 64-col tile

  for (int k0 = 0; k0 < K; k0 += 64) {
    const int h = k0 >> 6;  // head index, uniform this K-step
    // ---- fused A staging: a = (O0 + O1) / (L0 + L1), rounded once to bf16
#pragma unroll
    for (int i = 0; i < 2; i++) {
      const int ar = row0 + w * 16 + 8 * i + rr;
      const float L =
          Lpart[(size_t)h * T_SEQ + ar] +
          Lpart[(size_t)NHEAD * T_SEQ + (size_t)h * T_SEQ + ar];
      const float inv = 1.0f / L;
      const bf16x8 o0 = *reinterpret_cast<const bf16x8*>(
          Opart + (size_t)ar * C_EMB + k0 + c8);
      const bf16x8 o1 = *reinterpret_cast<const bf16x8*>(
          Opart + (size_t)T_SEQ * C_EMB + (size_t)ar * C_EMB + k0 + c8);
      bf16x8 av;
#pragma unroll
      for (int j = 0; j < 8; j++)
        av[j] = (bf16)(((float)o0[j] + (float)o1[j]) * inv);
      *reinterpret_cast<bf16x8*>(As + (w * 16 + 8 * i + rr) * 64 + c8) = av;
    }
    // ---- B staging unchanged (global_load_lds fast path)
    const bf16* gB = BT + (size_t)(col0 + w * 16 + rr) * K + k0 + c8;
#pragma unroll
    for (int i = 0; i < 2; i++)
      stage16(gB + (size_t)(8 * i) * K, Bs + (w * 16 + 8 * i) * 64);
    __syncthreads();

#pragma unroll
    for (int hh = 0; hh < 2; hh++) {
      bf16x8 af[2], bfv[2];
#pragma unroll
      for (int m = 0; m < 2; m++)
        af[m] = *reinterpret_cast<const bf16x8*>(
            As + (wr * 32 + m * 16 + l15) * 64 + hh * 32 + l4 * 8);
#pragma unroll
      for (int n = 0; n < 2; n++)
        bfv[n] = *reinterpret_cast<const bf16x8*>(
            Bs + (wc * 32 + n * 16 + l15) * 64 + hh * 32 + l4 * 8);
#pragma unroll
      for (int m = 0; m < 2; m++)
#pragma unroll
        for (int n = 0; n < 2; n++)
          acc[m][n] = __builtin_amdgcn_mfma_f32_16x16x32_bf16(af[m], bfv[n], acc[m][n], 0, 0, 0);
    }
    __syncthreads();
  }

  const int orow = row0 + wr * 32;
  const int ocol = col0 + wc * 32;
#pragma unroll
  for (int m = 0; m < 2; m++) {
#pragma unroll
    for (int n = 0; n < 2; n++) {
      const int c = ocol + n * 16 + l15;
#pragma unroll
      for (int j = 0; j < 4; j++) {
        const int r = orow + m * 16 + l4 * 4 + j;
        const size_t idx2 = (size_t)r * N + c;
        Cout[idx2] = (bf16)(res[idx2] + acc[m][n][j]);  // x1 = x + proj
      }
    }
  }
}

// ------------------------------------------------------------------ attention
// kqv [T][2304] bf16 : k at +0, q at +768 (PRE-SCALED by 0.125*log2e),
// v at +1536, head offset h*64.
// Writes UNNORMALIZED partials: Opart[z][4096][768] bf16, Lpart[z][12][4096] f32.
// 768 blocks (NZ=2), XCD-swizzled 1D grid: each XCD owns 3 (h,z) slabs x
// 32 qb (KV slab L2-resident, R12 mechanism). bounds(256,3) + VGPR ~80:
// PROVEN LOCAL OPTIMUM (R14/R16 allocator gambles both regressed).
// No-max softmax (P = exp2(st), |st| << 127): partials EXACTLY additive.
// T5 setprio around compute phase (neutral-to-positive, R18).
//
// 32x32x16 MFMA: wave owns 32 q (q = lane&31). Block = 4 waves (QB=128);
// KV tile = 128, 16 iters. Swapped QK^T: S^T = mfma32(A=K, B=Q); C-layout
// col=lane&31=q, row = (reg&3) + 8*(reg>>2) + 4*hi (hi = lane>>5).
// Key-relabel (R9-verified): position p -> label
// L(p) = 32t + 16*(s4>>1) + 8*hi_p + (r4 + 4*(s4&1)) so the PV B-frag is
// lane-local AND LINEAR in reg order (pairs feed v_cvt_pk_bf16_f32).
// V scattered to Vt[d][L] at staging. lsum via ones-MFMA (accL[0] = full
// row sum). Bank-conflict-free via odd-16B strides (K 144B, Vt 272B).
// K/V reg-staged with cross-iteration prefetch.
__global__ __launch_bounds__(256, 3)
void attn_fused(const bf16* __restrict__ kqv,
                bf16* __restrict__ Opart,
                float* __restrict__ Lpart) {
  // XCD-aware decode: fid&7 = XCD slot; each XCD owns 3 (h,z) slabs x 32 qb.
  const int fid = blockIdx.x;
  const int xs = fid & 7, r = fid >> 3;
  const int qb = r & 31;
  const int s = xs * 3 + (r >> 5);  // 0..23
  const int h = s % 12, z = s / 12;
  const int tid = threadIdx.x, w = tid >> 6, lane = tid & 63;
  const int l31 = lane & 31, hi = lane >> 5;

  __shared__ __align__(16) char KsB[128 * 144];  // K [pos][64d], stride 144B
  __shared__ __align__(16) char VtB[64 * 272];   // V^T [d][128 labels], 272B

  // Q fragments (B operand): col=q=l31, k = hi*8 + e (+16 per frag)
  const int qrow = qb * 128 + w * 32 + l31;
  const bf16* qp = kqv + (size_t)qrow * 2304 + 768 + h * 64;
  bf16x8 qf[4];
#pragma unroll
  for (int m = 0; m < 4; m++)
    qf[m] = *reinterpret_cast<const bf16x8*>(qp + hi * 8 + 16 * m);

  bf16x8 ones;
#pragma unroll
  for (int e = 0; e < 8; e++) ones[e] = (bf16)1.0f;

  f32x16 accO0 = zero16(), accO1 = zero16(), accL = zero16();

  // K staging: row = tid>>1 (0..127), 64B half = tid&1 (4 b128 chunks)
  const int krow = tid >> 1;
  const int kc0 = (tid & 1) * 4;
  // V staging: keys kb*4..+3, d = db*8..+7; label base (bijective in kb):
  const int kb = tid & 31, db = tid >> 5;
  const int lb = ((kb >> 3) & 3) * 32 + ((kb >> 2) & 1) * 16 + (kb & 1) * 8 +
                 ((kb >> 1) & 1) * 4;

  const int kt0 = z * 16;  // this block's 16 key-tiles

  bf16x8 kreg[4], vreg[4];
#define LOADKV(kt)                                                               \
  {                                                                              \
    const bf16* kp =                                                             \
        kqv + (size_t)((kt)*128 + krow) * 2304 + h * 64 + kc0 * 8;               \
    _Pragma("unroll") for (int i = 0; i < 4; i++)                                \
        kreg[i] = *reinterpret_cast<const bf16x8*>(kp + i * 8);                  \
    const bf16* vp =                                                             \
        kqv + (size_t)((kt)*128 + kb * 4) * 2304 + 1536 + h * 64 + db * 8;       \
    _Pragma("unroll") for (int r2 = 0; r2 < 4; r2++)                             \
        vreg[r2] = *reinterpret_cast<const bf16x8*>(vp + (size_t)r2 * 2304);     \
  }

  LOADKV(kt0);

  for (int kt = 0; kt < 16; kt++) {
    __syncthreads();
    // ---- LDS writes from registers
    {
      char* kdst = KsB + krow * 144;
#pragma unroll
      for (int i = 0; i < 4; i++)
        *reinterpret_cast<bf16x8*>(kdst + ((kc0 + i) * 16)) = kreg[i];
#pragma unroll
      for (int e = 0; e < 8; e++) {
        const int d = db * 8 + e;
        const bf16x4 pk4 = (bf16x4){vreg[0][e], vreg[1][e], vreg[2][e], vreg[3][e]};
        *reinterpret_cast<bf16x4*>(VtB + d * 272 + lb * 2) = pk4;
      }
    }
    __syncthreads();
    if (kt + 1 < 16) LOADKV(kt0 + kt + 1);  // prefetch flies during compute

    __builtin_amdgcn_s_setprio(1);  // T5: favor compute-phase waves

    // ---- QK^T (4 pos-tiles of 32) -> exp2 -> pack (LINEAR pairs -> cvt_pk)
    bf16x8 pb[8];
#pragma unroll
    for (int t = 0; t < 4; t++) {
      f32x16 st = zero16();
#pragma unroll
      for (int m = 0; m < 4; m++) {
        const bf16x8 kf = *reinterpret_cast<const bf16x8*>(
            KsB + (size_t)(32 * t + l31) * 144 + (2 * m + hi) * 16);
        st = __builtin_amdgcn_mfma_f32_32x32x16_bf16(kf, qf[m], st, 0, 0, 0);
      }
#pragma unroll
      for (int hf = 0; hf < 2; hf++) {
        bf16x8 p;
#pragma unroll
        for (int j = 0; j < 8; j++) p[j] = (bf16)EXP2(st[hf * 8 + j]);
        pb[2 * t + hf] = p;
      }
    }

    // ---- O^T += V^T @ P^T ; accL += ones @ P^T (full row sum, matrix pipe)
#pragma unroll
    for (int mk = 0; mk < 8; mk++) {
      const bf16x8 vf0 = *reinterpret_cast<const bf16x8*>(
          VtB + (size_t)l31 * 272 + (2 * mk + hi) * 16);
      accO0 = __builtin_amdgcn_mfma_f32_32x32x16_bf16(vf0, pb[mk], accO0, 0, 0, 0);
      const bf16x8 vf1 = *reinterpret_cast<const bf16x8*>(
          VtB + (size_t)(32 + l31) * 272 + (2 * mk + hi) * 16);
      accO1 = __builtin_amdgcn_mfma_f32_32x32x16_bf16(vf1, pb[mk], accO1, 0, 0, 0);
      accL = __builtin_amdgcn_mfma_f32_32x32x16_bf16(ones, pb[mk], accL, 0, 0, 0);
    }

    __builtin_amdgcn_s_setprio(0);
  }
#undef LOADKV

  // ---- epilogue: write unnormalized bf16 partials
  // accO row d = 32*dt + (reg&3) + 8*(reg>>2) + 4*hi, col q = l31
  bf16* Oq = Opart + (size_t)z * T_SEQ * C_EMB + (size_t)qrow * C_EMB + h * 64;
#pragma unroll
  for (int s4 = 0; s4 < 4; s4++) {
    const bf16x4 o0 = (bf16x4){(bf16)accO0[4 * s4 + 0], (bf16)accO0[4 * s4 + 1],
                               (bf16)accO0[4 * s4 + 2], (bf16)accO0[4 * s4 + 3]};
    *reinterpret_cast<bf16x4*>(Oq + 8 * s4 + 4 * hi) = o0;
    const bf16x4 o1 = (bf16x4){(bf16)accO1[4 * s4 + 0], (bf16)accO1[4 * s4 + 1],
                               (bf16)accO1[4 * s4 + 2], (bf16)accO1[4 * s4 + 3]};
    *reinterpret_cast<bf16x4*>(Oq + 32 + 8 * s4 + 4 * hi) = o1;
  }
  // accL: every row of D equals the full row-sum; lane l31 holds col q=l31.
  if (hi == 0)
    Lpart[(size_t)z * NHEAD * T_SEQ + (size_t)h * T_SEQ + qrow] = accL[0];
}

// ------------------------------------------------------------------ launch
extern "C" void kernel_launch(void* const* d_in, const int* in_sizes, int n_in,
                              void* d_out, int out_size, void* d_ws, size_t ws_size,
                              hipStream_t stream) {
  const float* x       = (const float*)d_in[0];
  const float* W_kqv   = (const float*)d_in[1];
  const float* W_proj  = (const float*)d_in[2];
  const float* W_fc    = (const float*)d_in[3];
  const float* b_fc    = (const float*)d_in[4];
  const float* W_cproj = (const float*)d_in[5];
  float* outp = (float*)d_out;

  char* p = (char*)d_ws;
  bf16* Wkqv_t  = (bf16*)p; p += (size_t)2304 * 768 * 2;
  bf16* Wproj_t = (bf16*)p; p += (size_t)768 * 768 * 2;
  bf16* Wfc_t   = (bf16*)p; p += (size_t)1536 * 768 * 2;
  bf16* Wcp_t   = (bf16*)p; p += (size_t)768 * 1536 * 2;
  bf16* A1      = (bf16*)p; p += (size_t)4096 * 768 * 2;   // LN1 out
  bf16* KQV     = (bf16*)p; p += (size_t)4096 * 2304 * 2;  // aliased: A2 | Hg
  bf16* x1      = (bf16*)p; p += (size_t)4096 * 768 * 2;   // bf16 residual
  bf16* Opart   = (bf16*)p; p += (size_t)NZ * 4096 * 768 * 2;
  float* Lpart  = (float*)p; p += (size_t)NZ * NHEAD * 4096 * 4;
  bf16* A2     = KQV;
  bf16* Hg     = KQV + (size_t)4096 * 768;

  // prep: all 4 weight transposes + LN1 in one launch (independent work)
  prep<<<8704, 256, 0, stream>>>(x, A1, W_kqv, Wkqv_t, W_proj, Wproj_t,
                                 W_fc, Wfc_t, W_cproj, Wcp_t);
  gemm_bt<4, 128><<<1152, 256, 0, stream>>>(A1, Wkqv_t, KQV, nullptr, nullptr,
                                            4096, 2304, 768);
  attn_fused<<<768, 256, 0, stream>>>(KQV, Opart, Lpart);
  // proj with FUSED combine (normalizes Opart in its A-staging)
  gemm_proj<<<768, 256, 0, stream>>>(Opart, Lpart, Wproj_t, x1, x);
  ln_rows<<<1024, 256, 0, stream>>>(x1, A2);
  gemm_bt<2, 64><<<1536, 256, 0, stream>>>(A2, Wfc_t, Hg, nullptr, b_fc,
                                           4096, 1536, 768);
  gemm_bt<3, 64><<<768, 256, 0, stream>>>(Hg, Wcp_t, outp, x1, nullptr,
                                          4096, 768, 1536);
}